// Round 4
// baseline (1078.739 us; speedup 1.0000x reference)
//
#include <hip/hip_runtime.h>
#include <hip/hip_cooperative_groups.h>
#include <math.h>

namespace cg = cooperative_groups;

namespace {

constexpr int B_ = 32, K_ = 512, L_ = 6, D_ = 2048, H_ = 16, HD_ = 128;
constexpr int OBS_ = 128, MAXS_ = 512, A_ = 10;
constexpr int NCH = 64, WKEYS = 8;           // 64 chunks of 8 keys, one wave each
constexpr int KSPLIT = 8, KCHUNK = 256;      // matmul k-split
constexpr int NBLK = 256, NTHR = 512;        // fused: 1 block/CU guaranteed
constexpr float EPS = 1e-5f;
constexpr float INV_SCALE = 0.022097086912079608f; // 1/sqrt(2048)

struct Params {
  const float *x, *mem;
  const int *mask, *midx;
  const float *enc_w, *enc_b;
  const float *lnq_g, *lnq_b, *lnkv_g, *lnkv_b, *lnat_g, *lnat_b;
  const float *wq, *wk, *wv, *wo, *bo, *fc_w, *fc_b;
  const float *post_w, *post_b, *act_w, *act_b, *cri_w, *cri_b;
  float *out;
  float *pe, *h, *qW, *opre, *xr, *xn, *hid, *pm, *ps, *pctx, *part;
};

__device__ __forceinline__ float wsum64(float v) {
  v += __shfl_xor(v, 32); v += __shfl_xor(v, 16); v += __shfl_xor(v, 8);
  v += __shfl_xor(v, 4);  v += __shfl_xor(v, 2);  v += __shfl_xor(v, 1);
  return v;
}

// ======================= FUSED COOPERATIVE KERNEL (256 x 512) =======================

__global__ __launch_bounds__(NTHR, 2) void k_fused(Params P) {
  cg::grid_group grid = cg::this_grid();
  const int g = blockIdx.x, t = threadIdx.x;
  const int lane = t & 63, wv = t >> 6;
  __shared__ float smem[8320];

  // ---------------- phase 0: pe table (2 rows/block) + encoder ----------------
  {
    int b = g >> 3, ec = g & 7;
    if (t < 32) ((float4*)smem)[t] = ((const float4*)(P.x + b * OBS_))[t];
    int half = t >> 8, tt = t & 255;
    int s = g + 256 * half;
    float seqv = (float)(MAXS_ - 1 - s);
    const float c = 13.287712379549449f / 1024.0f; // log2(10000)/1024
    #pragma unroll
    for (int r = 0; r < 8; ++r) {
      int j = tt + 256 * r;
      int i = (j < 1024) ? j : j - 1024;
      float inv = exp2f(-c * (float)i);
      float a = seqv * inv;
      P.pe[(size_t)s * D_ + j] = (j < 1024) ? sinf(a) : cosf(a);
    }
    __syncthreads();
    if (t < 256) {
      int e = ec * 256 + t;
      const float* wr = P.enc_w + (size_t)e * OBS_;
      float acc = 0.f;
      #pragma unroll
      for (int o = 0; o < OBS_; o += 4) {
        float4 w = *(const float4*)(wr + o);
        acc += w.x * smem[o] + w.y * smem[o + 1] + w.z * smem[o + 2] + w.w * smem[o + 3];
      }
      P.h[(size_t)b * D_ + e] = acc + P.enc_b[e];
    }
  }
  grid.sync();

  // ---------------- layers ----------------
  for (int l = 0; l < L_; ++l) {
    const float* Wq = P.wq + (size_t)l * HD_ * HD_;
    const float* Wk = P.wk + (size_t)l * HD_ * HD_;
    const float* Wv = P.wv + (size_t)l * HD_ * HD_;
    const float* Wo = P.wo + (size_t)l * D_ * D_;
    const float* Fw = P.fc_w + (size_t)l * D_ * D_;
    const float* qg = P.lnq_g + (size_t)l * D_,  *qb = P.lnq_b + (size_t)l * D_;
    const float* kg = P.lnkv_g + (size_t)l * D_, *kb = P.lnkv_b + (size_t)l * D_;
    const float* ag = P.lnat_g + (size_t)l * D_, *ab = P.lnat_b + (size_t)l * D_;
    const float* bo_ = P.bo + (size_t)l * D_;
    const float* fb = P.fc_b + (size_t)l * D_;

    // ---- qw: q_=LN(h); q=Wq q_; qW=inv_scale*Wk^T q  (g<32 active) ----
    if (g < B_) {
      int b = g;
      float* qn = smem;            // 2048
      float* qs2 = smem + 2048;    // 2048
      float* rs = smem + 4096; float* rq = smem + 4104;
      float4 v0 = *(const float4*)(P.h + (size_t)b * D_ + t * 4);
      float ls = v0.x + v0.y + v0.z + v0.w;
      float lq = v0.x * v0.x + v0.y * v0.y + v0.z * v0.z + v0.w * v0.w;
      ls = wsum64(ls); lq = wsum64(lq);
      if (lane == 0) { rs[wv] = ls; rq[wv] = lq; }
      __syncthreads();
      float sum = 0.f, sq = 0.f;
      #pragma unroll
      for (int w = 0; w < 8; ++w) { sum += rs[w]; sq += rq[w]; }
      float mean = sum * (1.f / D_);
      float rstd = rsqrtf(sq * (1.f / D_) - mean * mean + EPS);
      {
        float4 g0 = *(const float4*)(qg + t * 4);
        float4 b0 = *(const float4*)(qb + t * 4);
        qn[t * 4 + 0] = (v0.x - mean) * rstd * g0.x + b0.x;
        qn[t * 4 + 1] = (v0.y - mean) * rstd * g0.y + b0.y;
        qn[t * 4 + 2] = (v0.z - mean) * rstd * g0.z + b0.z;
        qn[t * 4 + 3] = (v0.w - mean) * rstd * g0.w + b0.w;
      }
      __syncthreads();
      int qid = t >> 5, li = t & 31;     // 16 head-groups of 32 lanes
      for (int e = 0; e < 128; ++e) {
        float4 w0 = *(const float4*)(Wq + (size_t)e * HD_ + li * 4);
        float4 a0 = *(const float4*)(qn + qid * HD_ + li * 4);
        float acc = w0.x * a0.x + w0.y * a0.y + w0.z * a0.z + w0.w * a0.w;
        acc += __shfl_xor(acc, 1); acc += __shfl_xor(acc, 2);
        acc += __shfl_xor(acc, 4); acc += __shfl_xor(acc, 8);
        acc += __shfl_xor(acc, 16);
        if (li == 0) qs2[qid * HD_ + e] = acc;
      }
      __syncthreads();
      #pragma unroll
      for (int r = 0; r < 4; ++r) {
        int j = t + 512 * r;
        int hh = j >> 7, d = j & 127;
        const float* qv = qs2 + hh * HD_;
        float acc = 0.f;
        for (int e = 0; e < HD_; ++e) acc += qv[e] * Wk[(size_t)e * HD_ + d];
        P.qW[(size_t)b * D_ + j] = acc * INV_SCALE;
      }
    }
    grid.sync();

    // ---- attention: 8 waves/block, wave-autonomous 8 keys ----
    {
      int b = g >> 3;
      int wid = t >> 6, l64 = t & 63;
      int ch = (g & 7) * 8 + wid;          // 0..63
      int hi = l64 >> 5, ll = l64 & 31;
      float* gs = smem; float* bs = smem + 2048; float* qs = smem + 4096;
      for (int i = t; i < D_ / 4; i += NTHR) {
        ((float4*)gs)[i] = ((const float4*)kg)[i];
        ((float4*)bs)[i] = ((const float4*)kb)[i];
        ((float4*)qs)[i] = ((const float4*)(P.qW + (size_t)b * D_))[i];
      }
      __syncthreads();
      float m[8], s[8];
      float4 ctx[8];
      #pragma unroll
      for (int i = 0; i < 8; ++i) {
        m[i] = -INFINITY; s[i] = 0.f; ctx[i] = {0.f, 0.f, 0.f, 0.f};
      }
      const size_t browbase = ((size_t)b * K_) * (L_ * D_) + (size_t)l * D_;
      int kk0 = ch * WKEYS;
      for (int kk = kk0; kk < kk0 + WKEYS; ++kk) {
        if (P.mask[b * K_ + kk] == 0) continue;   // wave-uniform
        int pidx = P.midx[b * K_ + kk];
        const float4* mp = (const float4*)(P.mem + browbase + (size_t)kk * (L_ * D_));
        const float4* pp = (const float4*)(P.pe + (size_t)pidx * D_);
        float4 xv[8];
        #pragma unroll
        for (int i = 0; i < 8; ++i) {
          float4 a = mp[i * 64 + l64];
          float4 c = pp[i * 64 + l64];
          xv[i] = {a.x + c.x, a.y + c.y, a.z + c.z, a.w + c.w};
        }
        float ls = 0.f, lq = 0.f;
        #pragma unroll
        for (int i = 0; i < 8; ++i) {
          ls += xv[i].x + xv[i].y + xv[i].z + xv[i].w;
          lq += xv[i].x * xv[i].x + xv[i].y * xv[i].y + xv[i].z * xv[i].z + xv[i].w * xv[i].w;
        }
        ls = wsum64(ls); lq = wsum64(lq);
        float mean = ls * (1.f / D_);
        float rstd = rsqrtf(lq * (1.f / D_) - mean * mean + EPS);
        #pragma unroll
        for (int i = 0; i < 8; ++i) {
          int idx = i * 64 + l64;
          float4 g4 = ((const float4*)gs)[idx];
          float4 b4 = ((const float4*)bs)[idx];
          float4 q4 = ((const float4*)qs)[idx];
          float4 kv;
          kv.x = (xv[i].x - mean) * rstd * g4.x + b4.x;
          kv.y = (xv[i].y - mean) * rstd * g4.y + b4.y;
          kv.z = (xv[i].z - mean) * rstd * g4.z + b4.z;
          kv.w = (xv[i].w - mean) * rstd * g4.w + b4.w;
          float p = kv.x * q4.x + kv.y * q4.y + kv.z * q4.z + kv.w * q4.w;
          p += __shfl_xor(p, 1); p += __shfl_xor(p, 2); p += __shfl_xor(p, 4);
          p += __shfl_xor(p, 8); p += __shfl_xor(p, 16);
          float mn = fmaxf(m[i], p);
          float sc = __expf(m[i] - mn);
          float w = __expf(p - mn);
          s[i] = s[i] * sc + w;
          ctx[i].x = ctx[i].x * sc + w * kv.x;
          ctx[i].y = ctx[i].y * sc + w * kv.y;
          ctx[i].z = ctx[i].z * sc + w * kv.z;
          ctx[i].w = ctx[i].w * sc + w * kv.w;
          m[i] = mn;
        }
      }
      #pragma unroll
      for (int i = 0; i < 8; ++i) {
        int head = 2 * i + hi;
        size_t base = (size_t)(b * H_ + head) * NCH + ch;
        *(float4*)(P.pctx + base * HD_ + 4 * ll) = ctx[i];
        if (ll == 0) { P.pm[base] = m[i]; P.ps[base] = s[i]; }
      }
    }
    grid.sync();

    // ---- merge partials + Wv  (2 heads per block) ----
    {
      int b = g >> 3;
      int hh = (g & 7) * 2 + (t >> 8);
      int tt = t & 255;
      float* cs = smem + (t >> 8) * 128;
      if (tt < 128) {
        size_t base = (size_t)(b * H_ + hh) * NCH;
        float m = -INFINITY;
        for (int c = 0; c < NCH; ++c) m = fmaxf(m, P.pm[base + c]);
        float stot = 0.f, acc = 0.f;
        for (int c = 0; c < NCH; ++c) {
          float wc = __expf(P.pm[base + c] - m);
          stot += P.ps[base + c] * wc;
          acc += P.pctx[(base + c) * HD_ + tt] * wc;
        }
        cs[tt] = (stot > 0.f) ? acc / stot : 0.f;
      }
      __syncthreads();
      if (tt < 128) {
        const float* wr = Wv + (size_t)tt * HD_;
        float o = 0.f;
        for (int d = 0; d < HD_; ++d) o += wr[d] * cs[d];
        P.opre[(size_t)b * D_ + hh * HD_ + tt] = o;
      }
    }
    grid.sync();

    // ---- xr = opre @ Wo^T + bo + h ; xn = LN(xr) ----
    {
      int et = g >> 3, kc = g & 7;
      float (*xs)[260] = (float (*)[260])smem;
      #pragma unroll
      for (int r = 0; r < 4; ++r) {
        int fi = (r * NTHR + t) * 4;
        int b = fi >> 8, k0 = fi & 255;
        *(float4*)&xs[b][k0] = *(const float4*)(P.opre + (size_t)b * D_ + kc * KCHUNK + k0);
      }
      __syncthreads();
      int b = t & 31, eg = t >> 5;    // 16 groups x 4 rows
      const float* wbase = Wo + (size_t)(et * 64 + eg * 4) * D_ + kc * KCHUNK;
      float acc[4] = {0.f, 0.f, 0.f, 0.f};
      for (int j = 0; j < KCHUNK / 4; ++j) {
        float4 x4 = *(const float4*)&xs[b][4 * j];
        #pragma unroll
        for (int i = 0; i < 4; ++i) {
          float4 w4 = *(const float4*)(wbase + (size_t)i * D_ + 4 * j);
          acc[i] += w4.x * x4.x + w4.y * x4.y + w4.z * x4.z + w4.w * x4.w;
        }
      }
      float4 o0 = {acc[0], acc[1], acc[2], acc[3]};
      *(float4*)(P.part + ((size_t)b * KSPLIT + kc) * D_ + et * 64 + eg * 4) = o0;
      __syncthreads();
    }
    grid.sync();
    if (g < B_) {
      int b = g;
      float* rs = smem; float* rq = smem + 8;
      float4 a = {0.f, 0.f, 0.f, 0.f};
      for (int kc = 0; kc < KSPLIT; ++kc) {
        float4 p = ((const float4*)(P.part + ((size_t)b * KSPLIT + kc) * D_))[t];
        a.x += p.x; a.y += p.y; a.z += p.z; a.w += p.w;
      }
      float4 b4 = ((const float4*)bo_)[t];
      float4 h4 = ((const float4*)(P.h + (size_t)b * D_))[t];
      a.x += b4.x + h4.x; a.y += b4.y + h4.y; a.z += b4.z + h4.z; a.w += b4.w + h4.w;
      float ls = a.x + a.y + a.z + a.w;
      float lq = a.x * a.x + a.y * a.y + a.z * a.z + a.w * a.w;
      ls = wsum64(ls); lq = wsum64(lq);
      if (lane == 0) { rs[wv] = ls; rq[wv] = lq; }
      __syncthreads();
      float sum = 0.f, sq = 0.f;
      #pragma unroll
      for (int w = 0; w < 8; ++w) { sum += rs[w]; sq += rq[w]; }
      float mean = sum * (1.f / D_);
      float rstd = rsqrtf(sq * (1.f / D_) - mean * mean + EPS);
      ((float4*)(P.xr + (size_t)b * D_))[t] = a;
      float4 g4 = ((const float4*)ag)[t];
      float4 bb = ((const float4*)ab)[t];
      float4 n;
      n.x = (a.x - mean) * rstd * g4.x + bb.x;
      n.y = (a.y - mean) * rstd * g4.y + bb.y;
      n.z = (a.z - mean) * rstd * g4.z + bb.z;
      n.w = (a.w - mean) * rstd * g4.w + bb.w;
      ((float4*)(P.xn + (size_t)b * D_))[t] = n;
    }
    grid.sync();

    // ---- h = relu(xn @ Fw^T + Fb) + xr ----
    {
      int et = g >> 3, kc = g & 7;
      float (*xs)[260] = (float (*)[260])smem;
      #pragma unroll
      for (int r = 0; r < 4; ++r) {
        int fi = (r * NTHR + t) * 4;
        int b = fi >> 8, k0 = fi & 255;
        *(float4*)&xs[b][k0] = *(const float4*)(P.xn + (size_t)b * D_ + kc * KCHUNK + k0);
      }
      __syncthreads();
      int b = t & 31, eg = t >> 5;
      const float* wbase = Fw + (size_t)(et * 64 + eg * 4) * D_ + kc * KCHUNK;
      float acc[4] = {0.f, 0.f, 0.f, 0.f};
      for (int j = 0; j < KCHUNK / 4; ++j) {
        float4 x4 = *(const float4*)&xs[b][4 * j];
        #pragma unroll
        for (int i = 0; i < 4; ++i) {
          float4 w4 = *(const float4*)(wbase + (size_t)i * D_ + 4 * j);
          acc[i] += w4.x * x4.x + w4.y * x4.y + w4.z * x4.z + w4.w * x4.w;
        }
      }
      float4 o0 = {acc[0], acc[1], acc[2], acc[3]};
      *(float4*)(P.part + ((size_t)b * KSPLIT + kc) * D_ + et * 64 + eg * 4) = o0;
      __syncthreads();
    }
    grid.sync();
    if (g < B_) {
      int b = g;
      float4 a = {0.f, 0.f, 0.f, 0.f};
      for (int kc = 0; kc < KSPLIT; ++kc) {
        float4 p = ((const float4*)(P.part + ((size_t)b * KSPLIT + kc) * D_))[t];
        a.x += p.x; a.y += p.y; a.z += p.z; a.w += p.w;
      }
      float4 b4 = ((const float4*)fb)[t];
      a.x = fmaxf(a.x + b4.x, 0.f); a.y = fmaxf(a.y + b4.y, 0.f);
      a.z = fmaxf(a.z + b4.z, 0.f); a.w = fmaxf(a.w + b4.w, 0.f);
      float4 h4 = ((const float4*)(P.xr + (size_t)b * D_))[t];
      a.x += h4.x; a.y += h4.y; a.z += h4.z; a.w += h4.w;
      ((float4*)(P.h + (size_t)b * D_))[t] = a;
    }
    grid.sync();
  }

  // ---------------- post + heads ----------------
  {
    int et = g >> 3, kc = g & 7;
    float (*xs)[260] = (float (*)[260])smem;
    #pragma unroll
    for (int r = 0; r < 4; ++r) {
      int fi = (r * NTHR + t) * 4;
      int b = fi >> 8, k0 = fi & 255;
      *(float4*)&xs[b][k0] = *(const float4*)(P.h + (size_t)b * D_ + kc * KCHUNK + k0);
    }
    __syncthreads();
    int b = t & 31, eg = t >> 5;
    const float* wbase = P.post_w + (size_t)(et * 64 + eg * 4) * D_ + kc * KCHUNK;
    float acc[4] = {0.f, 0.f, 0.f, 0.f};
    for (int j = 0; j < KCHUNK / 4; ++j) {
      float4 x4 = *(const float4*)&xs[b][4 * j];
      #pragma unroll
      for (int i = 0; i < 4; ++i) {
        float4 w4 = *(const float4*)(wbase + (size_t)i * D_ + 4 * j);
        acc[i] += w4.x * x4.x + w4.y * x4.y + w4.z * x4.z + w4.w * x4.w;
      }
    }
    float4 o0 = {acc[0], acc[1], acc[2], acc[3]};
    *(float4*)(P.part + ((size_t)b * KSPLIT + kc) * D_ + et * 64 + eg * 4) = o0;
    __syncthreads();
  }
  grid.sync();
  if (g < B_) {
    int b = g;
    float4 a = {0.f, 0.f, 0.f, 0.f};
    for (int kc = 0; kc < KSPLIT; ++kc) {
      float4 p = ((const float4*)(P.part + ((size_t)b * KSPLIT + kc) * D_))[t];
      a.x += p.x; a.y += p.y; a.z += p.z; a.w += p.w;
    }
    float4 b4 = ((const float4*)P.post_b)[t];
    a.x = fmaxf(a.x + b4.x, 0.f); a.y = fmaxf(a.y + b4.y, 0.f);
    a.z = fmaxf(a.z + b4.z, 0.f); a.w = fmaxf(a.w + b4.w, 0.f);
    ((float4*)(P.hid + (size_t)b * D_))[t] = a;
  }
  grid.sync();
  if (g < B_) {
    int b = g;
    ((float4*)smem)[t] = ((const float4*)(P.hid + (size_t)b * D_))[t];
    __syncthreads();
    int w = t >> 6;
    for (int j = w; j < A_ + 1; j += 8) {
      const float* wr = (j < A_) ? (P.act_w + (size_t)j * D_) : P.cri_w;
      float acc = 0.f;
      for (int i = lane; i < D_ / 4; i += 64) {
        float4 wv4 = ((const float4*)wr)[i];
        float4 xv = ((const float4*)smem)[i];
        acc += wv4.x * xv.x + wv4.y * xv.y + wv4.z * xv.z + wv4.w * xv.w;
      }
      acc = wsum64(acc);
      if (lane == 0)
        P.out[b * (A_ + 1) + j] = acc + ((j < A_) ? P.act_b[j] : P.cri_b[0]);
    }
  }
}

// ======================= FALLBACK MULTI-KERNEL PATH (round-2, known good) =======================

__global__ __launch_bounds__(256) void k_pe(float* __restrict__ pe) {
  int s = blockIdx.x, t = threadIdx.x;
  float seqv = (float)(MAXS_ - 1 - s);
  const float c = 13.287712379549449f / 1024.0f;
  for (int r = 0; r < 8; ++r) {
    int j = t + 256 * r;
    int i = (j < 1024) ? j : j - 1024;
    float inv = exp2f(-c * (float)i);
    float a = seqv * inv;
    pe[(size_t)s * D_ + j] = (j < 1024) ? sinf(a) : cosf(a);
  }
}

__global__ __launch_bounds__(128) void k_enc(const float* __restrict__ x,
                                             const float* __restrict__ ew,
                                             const float* __restrict__ eb,
                                             float* __restrict__ h) {
  int b = blockIdx.x, et = blockIdx.y, t = threadIdx.x;
  __shared__ float xs[OBS_];
  xs[t] = x[b * OBS_ + t];
  __syncthreads();
  int e = et * 128 + t;
  const float* wr = ew + (size_t)e * OBS_;
  float acc = eb[e];
  for (int o = 0; o < OBS_; ++o) acc += xs[o] * wr[o];
  h[(size_t)b * D_ + e] = acc;
}

__global__ __launch_bounds__(256) void k_qw(const float* __restrict__ h,
                                            const float* __restrict__ g,
                                            const float* __restrict__ bvec,
                                            const float* __restrict__ Wq,
                                            const float* __restrict__ Wk,
                                            float* __restrict__ qW) {
  int b = blockIdx.x, t = threadIdx.x;
  int lane = t & 63, wv = t >> 6;
  __shared__ float qn[D_];
  __shared__ float qs[D_];
  __shared__ float rs[4], rq[4];
  float4 v0 = *(const float4*)(h + (size_t)b * D_ + t * 8);
  float4 v1 = *(const float4*)(h + (size_t)b * D_ + t * 8 + 4);
  float ls = v0.x + v0.y + v0.z + v0.w + v1.x + v1.y + v1.z + v1.w;
  float lq = v0.x * v0.x + v0.y * v0.y + v0.z * v0.z + v0.w * v0.w +
             v1.x * v1.x + v1.y * v1.y + v1.z * v1.z + v1.w * v1.w;
  ls = wsum64(ls); lq = wsum64(lq);
  if (lane == 0) { rs[wv] = ls; rq[wv] = lq; }
  __syncthreads();
  float sum = rs[0] + rs[1] + rs[2] + rs[3];
  float sq  = rq[0] + rq[1] + rq[2] + rq[3];
  float mean = sum * (1.f / D_);
  float rstd = rsqrtf(sq * (1.f / D_) - mean * mean + EPS);
  {
    float4 g0 = *(const float4*)(g + t * 8);
    float4 g1 = *(const float4*)(g + t * 8 + 4);
    float4 b0 = *(const float4*)(bvec + t * 8);
    float4 b1 = *(const float4*)(bvec + t * 8 + 4);
    qn[t * 8 + 0] = (v0.x - mean) * rstd * g0.x + b0.x;
    qn[t * 8 + 1] = (v0.y - mean) * rstd * g0.y + b0.y;
    qn[t * 8 + 2] = (v0.z - mean) * rstd * g0.z + b0.z;
    qn[t * 8 + 3] = (v0.w - mean) * rstd * g0.w + b0.w;
    qn[t * 8 + 4] = (v1.x - mean) * rstd * g1.x + b1.x;
    qn[t * 8 + 5] = (v1.y - mean) * rstd * g1.y + b1.y;
    qn[t * 8 + 6] = (v1.z - mean) * rstd * g1.z + b1.z;
    qn[t * 8 + 7] = (v1.w - mean) * rstd * g1.w + b1.w;
  }
  __syncthreads();
  int qid = t >> 4, li = t & 15;
  for (int e = 0; e < 128; ++e) {
    const float4* wr = (const float4*)(Wq + (size_t)e * HD_ + li * 8);
    const float4* qv = (const float4*)(qn + qid * HD_ + li * 8);
    float4 w0 = wr[0], w1 = wr[1], a0 = qv[0], a1 = qv[1];
    float acc = w0.x * a0.x + w0.y * a0.y + w0.z * a0.z + w0.w * a0.w +
                w1.x * a1.x + w1.y * a1.y + w1.z * a1.z + w1.w * a1.w;
    acc += __shfl_xor(acc, 1); acc += __shfl_xor(acc, 2);
    acc += __shfl_xor(acc, 4); acc += __shfl_xor(acc, 8);
    if (li == 0) qs[qid * HD_ + e] = acc;
  }
  __syncthreads();
  for (int r = 0; r < 8; ++r) {
    int j = t + 256 * r;
    int hh = j >> 7, d = j & 127;
    const float* qv = qs + hh * HD_;
    float acc = 0.f;
    for (int e = 0; e < HD_; ++e) acc += qv[e] * Wk[(size_t)e * HD_ + d];
    qW[(size_t)b * D_ + j] = acc * INV_SCALE;
  }
}

__global__ __launch_bounds__(256) void k_attn(const float* __restrict__ mem,
                                              const float* __restrict__ pe,
                                              const int* __restrict__ mask,
                                              const int* __restrict__ midx,
                                              const float* __restrict__ g,
                                              const float* __restrict__ bvec,
                                              const float* __restrict__ qW,
                                              float* __restrict__ pm,
                                              float* __restrict__ ps,
                                              float* __restrict__ pctx,
                                              int layer) {
  int b = blockIdx.x;
  int t = threadIdx.x;
  int wid = t >> 6, l = t & 63;
  int ch = blockIdx.y * 4 + wid;
  int hi = l >> 5, ll = l & 31;
  __shared__ float gs[D_], bs[D_], qs[D_];
  for (int i = t; i < D_ / 4; i += 256) {
    ((float4*)gs)[i] = ((const float4*)g)[i];
    ((float4*)bs)[i] = ((const float4*)bvec)[i];
    ((float4*)qs)[i] = ((const float4*)(qW + (size_t)b * D_))[i];
  }
  __syncthreads();
  float m[8], s[8];
  float4 ctx[8];
  #pragma unroll
  for (int i = 0; i < 8; ++i) {
    m[i] = -INFINITY; s[i] = 0.f; ctx[i] = {0.f, 0.f, 0.f, 0.f};
  }
  const size_t browbase = ((size_t)b * K_) * (L_ * D_) + (size_t)layer * D_;
  int kk0 = ch * WKEYS;
  for (int kk = kk0; kk < kk0 + WKEYS; ++kk) {
    if (mask[b * K_ + kk] == 0) continue;
    int pidx = midx[b * K_ + kk];
    const float4* mp = (const float4*)(mem + browbase + (size_t)kk * (L_ * D_));
    const float4* pp = (const float4*)(pe + (size_t)pidx * D_);
    float4 xv[8];
    #pragma unroll
    for (int i = 0; i < 8; ++i) {
      float4 a = mp[i * 64 + l];
      float4 c = pp[i * 64 + l];
      xv[i] = {a.x + c.x, a.y + c.y, a.z + c.z, a.w + c.w};
    }
    float ls = 0.f, lq = 0.f;
    #pragma unroll
    for (int i = 0; i < 8; ++i) {
      ls += xv[i].x + xv[i].y + xv[i].z + xv[i].w;
      lq += xv[i].x * xv[i].x + xv[i].y * xv[i].y + xv[i].z * xv[i].z + xv[i].w * xv[i].w;
    }
    ls = wsum64(ls); lq = wsum64(lq);
    float mean = ls * (1.f / D_);
    float rstd = rsqrtf(lq * (1.f / D_) - mean * mean + EPS);
    #pragma unroll
    for (int i = 0; i < 8; ++i) {
      int idx = i * 64 + l;
      float4 g4 = ((const float4*)gs)[idx];
      float4 b4 = ((const float4*)bs)[idx];
      float4 q4 = ((const float4*)qs)[idx];
      float4 kv;
      kv.x = (xv[i].x - mean) * rstd * g4.x + b4.x;
      kv.y = (xv[i].y - mean) * rstd * g4.y + b4.y;
      kv.z = (xv[i].z - mean) * rstd * g4.z + b4.z;
      kv.w = (xv[i].w - mean) * rstd * g4.w + b4.w;
      float p = kv.x * q4.x + kv.y * q4.y + kv.z * q4.z + kv.w * q4.w;
      p += __shfl_xor(p, 1); p += __shfl_xor(p, 2); p += __shfl_xor(p, 4);
      p += __shfl_xor(p, 8); p += __shfl_xor(p, 16);
      float mn = fmaxf(m[i], p);
      float sc = __expf(m[i] - mn);
      float w = __expf(p - mn);
      s[i] = s[i] * sc + w;
      ctx[i].x = ctx[i].x * sc + w * kv.x;
      ctx[i].y = ctx[i].y * sc + w * kv.y;
      ctx[i].z = ctx[i].z * sc + w * kv.z;
      ctx[i].w = ctx[i].w * sc + w * kv.w;
      m[i] = mn;
    }
  }
  #pragma unroll
  for (int i = 0; i < 8; ++i) {
    int head = 2 * i + hi;
    size_t base = (size_t)(b * H_ + head) * NCH + ch;
    *(float4*)(pctx + base * HD_ + 4 * ll) = ctx[i];
    if (ll == 0) { pm[base] = m[i]; ps[base] = s[i]; }
  }
}

__global__ __launch_bounds__(128) void k_reduce(const float* __restrict__ pm,
                                                const float* __restrict__ ps,
                                                const float* __restrict__ pctx,
                                                const float* __restrict__ Wv,
                                                float* __restrict__ opre) {
  int hh = blockIdx.x, b = blockIdx.y;
  int t = threadIdx.x;
  size_t base = (size_t)(b * H_ + hh) * NCH;
  float m = -INFINITY;
  for (int c = 0; c < NCH; ++c) m = fmaxf(m, pm[base + c]);
  float stot = 0.f, acc = 0.f;
  for (int c = 0; c < NCH; ++c) {
    float wc = __expf(pm[base + c] - m);
    stot += ps[base + c] * wc;
    acc += pctx[(base + c) * HD_ + t] * wc;
  }
  float ctxn = (stot > 0.f) ? acc / stot : 0.f;
  __shared__ float cs[HD_];
  cs[t] = ctxn;
  __syncthreads();
  const float* wr = Wv + (size_t)t * HD_;
  float o = 0.f;
  for (int d = 0; d < HD_; ++d) o += wr[d] * cs[d];
  opre[(size_t)b * D_ + hh * HD_ + t] = o;
}

__global__ __launch_bounds__(256) void k_mv(const float* __restrict__ X,
                                            const float* __restrict__ W,
                                            float* __restrict__ part) {
  int et = blockIdx.x, kc = blockIdx.y;
  int t = threadIdx.x;
  __shared__ float xs[32][260];
  for (int r = 0; r < 8; ++r) {
    int i = t + 256 * r;
    int b = i >> 6, j = i & 63;
    float4 v = *(const float4*)(X + (size_t)b * D_ + kc * KCHUNK + 4 * j);
    *(float4*)(&xs[b][4 * j]) = v;
  }
  __syncthreads();
  int b = t & 31, eg = t >> 5;
  const float* wbase = W + (size_t)(et * 64 + eg * 8) * D_ + kc * KCHUNK;
  float acc[8] = {0.f, 0.f, 0.f, 0.f, 0.f, 0.f, 0.f, 0.f};
  for (int j = 0; j < 64; ++j) {
    float4 x4 = *(const float4*)(&xs[b][4 * j]);
    #pragma unroll
    for (int i = 0; i < 8; ++i) {
      float4 w4 = *(const float4*)(wbase + (size_t)i * D_ + 4 * j);
      acc[i] += w4.x * x4.x + w4.y * x4.y + w4.z * x4.z + w4.w * x4.w;
    }
  }
  float* pb = part + ((size_t)b * KSPLIT + kc) * D_ + et * 64 + eg * 8;
  float4 o0 = {acc[0], acc[1], acc[2], acc[3]};
  float4 o1 = {acc[4], acc[5], acc[6], acc[7]};
  *(float4*)pb = o0;
  *(float4*)(pb + 4) = o1;
}

__global__ __launch_bounds__(256) void k_mvred_ln(const float* __restrict__ part,
                                                  const float* __restrict__ bias,
                                                  const float* __restrict__ res,
                                                  const float* __restrict__ g,
                                                  const float* __restrict__ bvec,
                                                  float* __restrict__ xr,
                                                  float* __restrict__ xn) {
  int b = blockIdx.x, t = threadIdx.x;
  int lane = t & 63, wv = t >> 6;
  __shared__ float rs[4], rq[4];
  float4 v[2];
  float ls = 0.f, lq = 0.f;
  #pragma unroll
  for (int r = 0; r < 2; ++r) {
    int e4 = t + 256 * r;
    float4 a = {0.f, 0.f, 0.f, 0.f};
    for (int kc = 0; kc < KSPLIT; ++kc) {
      float4 p = ((const float4*)(part + ((size_t)b * KSPLIT + kc) * D_))[e4];
      a.x += p.x; a.y += p.y; a.z += p.z; a.w += p.w;
    }
    float4 b4 = ((const float4*)bias)[e4];
    float4 h4 = ((const float4*)(res + (size_t)b * D_))[e4];
    a.x += b4.x + h4.x; a.y += b4.y + h4.y; a.z += b4.z + h4.z; a.w += b4.w + h4.w;
    v[r] = a;
    ls += a.x + a.y + a.z + a.w;
    lq += a.x * a.x + a.y * a.y + a.z * a.z + a.w * a.w;
  }
  ls = wsum64(ls); lq = wsum64(lq);
  if (lane == 0) { rs[wv] = ls; rq[wv] = lq; }
  __syncthreads();
  float sum = rs[0] + rs[1] + rs[2] + rs[3];
  float sq  = rq[0] + rq[1] + rq[2] + rq[3];
  float mean = sum * (1.f / D_);
  float rstd = rsqrtf(sq * (1.f / D_) - mean * mean + EPS);
  #pragma unroll
  for (int r = 0; r < 2; ++r) {
    int e4 = t + 256 * r;
    float4 a = v[r];
    ((float4*)(xr + (size_t)b * D_))[e4] = a;
    float4 g4 = ((const float4*)g)[e4];
    float4 b4 = ((const float4*)bvec)[e4];
    float4 n;
    n.x = (a.x - mean) * rstd * g4.x + b4.x;
    n.y = (a.y - mean) * rstd * g4.y + b4.y;
    n.z = (a.z - mean) * rstd * g4.z + b4.z;
    n.w = (a.w - mean) * rstd * g4.w + b4.w;
    ((float4*)(xn + (size_t)b * D_))[e4] = n;
  }
}

__global__ __launch_bounds__(256) void k_mvred_relu(const float* __restrict__ part,
                                                    const float* __restrict__ bias,
                                                    const float* __restrict__ res,
                                                    float* __restrict__ out) {
  int b = blockIdx.x, t = threadIdx.x;
  #pragma unroll
  for (int r = 0; r < 2; ++r) {
    int e4 = t + 256 * r;
    float4 a = {0.f, 0.f, 0.f, 0.f};
    for (int kc = 0; kc < KSPLIT; ++kc) {
      float4 p = ((const float4*)(part + ((size_t)b * KSPLIT + kc) * D_))[e4];
      a.x += p.x; a.y += p.y; a.z += p.z; a.w += p.w;
    }
    float4 b4 = ((const float4*)bias)[e4];
    a.x = fmaxf(a.x + b4.x, 0.f); a.y = fmaxf(a.y + b4.y, 0.f);
    a.z = fmaxf(a.z + b4.z, 0.f); a.w = fmaxf(a.w + b4.w, 0.f);
    if (res) {
      float4 h4 = ((const float4*)(res + (size_t)b * D_))[e4];
      a.x += h4.x; a.y += h4.y; a.z += h4.z; a.w += h4.w;
    }
    ((float4*)(out + (size_t)b * D_))[e4] = a;
  }
}

__global__ __launch_bounds__(256) void k_heads(const float* __restrict__ hid,
                                               const float* __restrict__ aw,
                                               const float* __restrict__ ab,
                                               const float* __restrict__ cw,
                                               const float* __restrict__ cb,
                                               float* __restrict__ out) {
  int b = blockIdx.x, j = blockIdx.y;
  int t = threadIdx.x, lane = t & 63, wv = t >> 6;
  const float* wr = (j < A_) ? (aw + (size_t)j * D_) : cw;
  float acc = 0.f;
  for (int i = t; i < D_ / 4; i += 256) {
    float4 w = ((const float4*)wr)[i];
    float4 xv = ((const float4*)(hid + (size_t)b * D_))[i];
    acc += w.x * xv.x + w.y * xv.y + w.z * xv.z + w.w * xv.w;
  }
  acc = wsum64(acc);
  __shared__ float r[4];
  if (lane == 0) r[wv] = acc;
  __syncthreads();
  if (t == 0) {
    float s = r[0] + r[1] + r[2] + r[3] + ((j < A_) ? ab[j] : cb[0]);
    out[b * (A_ + 1) + j] = s;
  }
}

} // namespace

extern "C" void kernel_launch(void* const* d_in, const int* in_sizes, int n_in,
                              void* d_out, int out_size, void* d_ws, size_t ws_size,
                              hipStream_t stream) {
  (void)in_sizes; (void)n_in; (void)out_size; (void)ws_size;
  Params p;
  p.x      = (const float*)d_in[0];
  p.mem    = (const float*)d_in[1];
  p.mask   = (const int*)d_in[2];
  p.midx   = (const int*)d_in[3];
  p.enc_w  = (const float*)d_in[4];
  p.enc_b  = (const float*)d_in[5];
  p.lnq_g  = (const float*)d_in[6];
  p.lnq_b  = (const float*)d_in[7];
  p.lnkv_g = (const float*)d_in[8];
  p.lnkv_b = (const float*)d_in[9];
  p.lnat_g = (const float*)d_in[10];
  p.lnat_b = (const float*)d_in[11];
  p.wq     = (const float*)d_in[12];
  p.wk     = (const float*)d_in[13];
  p.wv     = (const float*)d_in[14];
  p.wo     = (const float*)d_in[15];
  p.bo     = (const float*)d_in[16];
  p.fc_w   = (const float*)d_in[17];
  p.fc_b   = (const float*)d_in[18];
  p.post_w = (const float*)d_in[19];
  p.post_b = (const float*)d_in[20];
  p.act_w  = (const float*)d_in[21];
  p.act_b  = (const float*)d_in[22];
  p.cri_w  = (const float*)d_in[23];
  p.cri_b  = (const float*)d_in[24];
  p.out    = (float*)d_out;

  float* ws = (float*)d_ws;
  size_t off = 0;
  p.pe   = ws + off; off += (size_t)MAXS_ * D_;
  p.h    = ws + off; off += (size_t)B_ * D_;
  p.qW   = ws + off; off += (size_t)B_ * D_;
  p.opre = ws + off; off += (size_t)B_ * D_;
  p.xr   = ws + off; off += (size_t)B_ * D_;
  p.xn   = ws + off; off += (size_t)B_ * D_;
  p.hid  = ws + off; off += (size_t)B_ * D_;
  p.pm   = ws + off; off += (size_t)B_ * H_ * NCH;
  p.ps   = ws + off; off += (size_t)B_ * H_ * NCH;
  p.pctx = ws + off; off += (size_t)B_ * H_ * NCH * HD_;
  p.part = ws + off; off += (size_t)B_ * KSPLIT * D_;

  // --- decide: cooperative fused kernel, or multi-kernel fallback ---
  bool use_coop = false;
  {
    int dev = 0;
    (void)hipGetDevice(&dev);
    int coop = 0;
    (void)hipDeviceGetAttribute(&coop, hipDeviceAttributeCooperativeLaunch, dev);
    int ncu = 0;
    (void)hipDeviceGetAttribute(&ncu, hipDeviceAttributeMultiprocessorCount, dev);
    int maxb = 0;
    (void)hipOccupancyMaxActiveBlocksPerMultiprocessor(&maxb, k_fused, NTHR, 0);
    use_coop = (coop != 0) && ((long)maxb * (long)ncu >= (long)NBLK);
  }

  if (use_coop) {
    void* args[] = {&p};
    hipError_t e = hipLaunchCooperativeKernel(k_fused, dim3(NBLK), dim3(NTHR),
                                              args, 0, stream);
    if (e == hipSuccess) return;
    (void)hipGetLastError();  // clear, fall through to fallback
  }

  // ---------------- fallback: round-2 sequence ----------------
  hipLaunchKernelGGL(k_pe, dim3(MAXS_), dim3(256), 0, stream, p.pe);
  hipLaunchKernelGGL(k_enc, dim3(B_, D_ / 128), dim3(128), 0, stream,
                     p.x, p.enc_w, p.enc_b, p.h);
  for (int l = 0; l < L_; ++l) {
    const float* Wq = p.wq + (size_t)l * HD_ * HD_;
    const float* Wk = p.wk + (size_t)l * HD_ * HD_;
    const float* Wv = p.wv + (size_t)l * HD_ * HD_;
    const float* Wo = p.wo + (size_t)l * D_ * D_;
    const float* Fw = p.fc_w + (size_t)l * D_ * D_;
    hipLaunchKernelGGL(k_qw, dim3(B_), dim3(256), 0, stream,
                       p.h, p.lnq_g + (size_t)l * D_, p.lnq_b + (size_t)l * D_, Wq, Wk, p.qW);
    hipLaunchKernelGGL(k_attn, dim3(B_, NCH / 4), dim3(256), 0, stream,
                       p.mem, p.pe, p.mask, p.midx,
                       p.lnkv_g + (size_t)l * D_, p.lnkv_b + (size_t)l * D_,
                       p.qW, p.pm, p.ps, p.pctx, l);
    hipLaunchKernelGGL(k_reduce, dim3(H_, B_), dim3(128), 0, stream,
                       p.pm, p.ps, p.pctx, Wv, p.opre);
    hipLaunchKernelGGL(k_mv, dim3(D_ / 64, KSPLIT), dim3(256), 0, stream, p.opre, Wo, p.part);
    hipLaunchKernelGGL(k_mvred_ln, dim3(B_), dim3(256), 0, stream,
                       p.part, p.bo + (size_t)l * D_, p.h,
                       p.lnat_g + (size_t)l * D_, p.lnat_b + (size_t)l * D_, p.xr, p.xn);
    hipLaunchKernelGGL(k_mv, dim3(D_ / 64, KSPLIT), dim3(256), 0, stream, p.xn, Fw, p.part);
    hipLaunchKernelGGL(k_mvred_relu, dim3(B_), dim3(256), 0, stream,
                       p.part, p.fc_b + (size_t)l * D_, p.xr, p.h);
  }
  hipLaunchKernelGGL(k_mv, dim3(D_ / 64, KSPLIT), dim3(256), 0, stream, p.h, p.post_w, p.part);
  hipLaunchKernelGGL(k_mvred_relu, dim3(B_), dim3(256), 0, stream,
                     p.part, p.post_b, (const float*)nullptr, p.hid);
  hipLaunchKernelGGL(k_heads, dim3(B_, A_ + 1), dim3(256), 0, stream,
                     p.hid, p.act_w, p.act_b, p.cri_w, p.cri_b, p.out);
}